// Round 3
// baseline (553.445 us; speedup 1.0000x reference)
//
#include <hip/hip_runtime.h>
#include <hip/hip_bf16.h>
#include <stdint.h>

// Problem constants (from reference setup_inputs)
#define M_DIM   32768        // B*S = 32*1024
#define IN_DIM  1152
#define OUT_DIM 1152
#define R_DIM   64
#define QMAXF   255.0f

#define SBLOCKS     2048     // streaming pass blocks: 16 rows each
#define ROWS_PER_BLK 16
#define CHUNKS_PER_THREAD 9  // (16*1152/8)/256

typedef float  f32x4  __attribute__((ext_vector_type(4)));
typedef __bf16 bf16x8 __attribute__((ext_vector_type(8)));
typedef unsigned short u16x8 __attribute__((ext_vector_type(8)));

// RNE float -> bf16 bits (finite inputs only)
static __device__ __forceinline__ unsigned short f2bf(float f) {
    unsigned int u = __float_as_uint(f);
    unsigned int r = (u + 0x7fffu + ((u >> 16) & 1u)) >> 16;
    return (unsigned short)r;
}

// order-preserving float <-> uint32 bijection (for atomicMin/Max on floats)
static __device__ __forceinline__ unsigned int f2ord(float f) {
    unsigned int u = __float_as_uint(f);
    return (u & 0x80000000u) ? ~u : (u | 0x80000000u);
}
static __device__ __forceinline__ float ord2f(unsigned int m) {
    unsigned int u = (m & 0x80000000u) ? (m & 0x7fffffffu) : ~m;
    return __uint_as_float(u);
}

// column offset of chunk j relative to thread's base column: (j*2048) % 1152
__constant__ int CJ_TBL[9] = {0, 896, 640, 384, 128, 1024, 768, 512, 256};

// ---------------- Pass 1: weight fold + inv_s + atomic init (fused prep) ----
// Wc[o][i] = quant_w[o][i] + sum_r left_w[o][r] * right_w[r][i]
__global__ __launch_bounds__(256) void k_prep(const float* __restrict__ qw,
                                              const float* __restrict__ rw,
                                              const float* __restrict__ lw,
                                              const float* __restrict__ scales,
                                              unsigned short* __restrict__ wc,
                                              float* __restrict__ inv_s,
                                              unsigned int* __restrict__ qpa) {
    int idx = blockIdx.x * 256 + threadIdx.x;   // over OUT*IN, exact grid
    if (idx < IN_DIM) inv_s[idx] = 1.0f / scales[idx];
    if (idx == 0) { qpa[0] = 0xFFFFFFFFu; qpa[1] = 0u; }  // min/max identities
    int o = idx / IN_DIM;
    int i = idx - o * IN_DIM;
    float acc = qw[idx];
    #pragma unroll 8
    for (int r = 0; r < R_DIM; r++)
        acc += lw[o * R_DIM + r] * rw[r * IN_DIM + i];
    wc[idx] = f2bf(acc);
}

// ---------------- Pass 2: global min/max of x * inv_s (atomic finalize) -----
__global__ __launch_bounds__(256) void k_minmax(const float* __restrict__ x,
                                                const float* __restrict__ inv_s,
                                                unsigned int* __restrict__ qpa) {
    const int t = threadIdx.x;
    const size_t base = (size_t)blockIdx.x * (ROWS_PER_BLK * IN_DIM);
    int c0 = t * 8; if (c0 >= IN_DIM) c0 -= IN_DIM;
    float mn = 3.4e38f, mx = -3.4e38f;
    #pragma unroll 3
    for (int j = 0; j < CHUNKS_PER_THREAD; j++) {
        size_t off = base + (size_t)(j * 256 + t) * 8;
        float4 x0 = *(const float4*)(x + off);
        float4 x1 = *(const float4*)(x + off + 4);
        int cj = c0 + CJ_TBL[j]; if (cj >= IN_DIM) cj -= IN_DIM;
        float4 s0 = *(const float4*)(inv_s + cj);
        float4 s1 = *(const float4*)(inv_s + cj + 4);
        float a0 = x0.x * s0.x, a1 = x0.y * s0.y, a2 = x0.z * s0.z, a3 = x0.w * s0.w;
        float a4 = x1.x * s1.x, a5 = x1.y * s1.y, a6 = x1.z * s1.z, a7 = x1.w * s1.w;
        mn = fminf(mn, fminf(fminf(fminf(a0, a1), fminf(a2, a3)),
                             fminf(fminf(a4, a5), fminf(a6, a7))));
        mx = fmaxf(mx, fmaxf(fmaxf(fmaxf(a0, a1), fmaxf(a2, a3)),
                             fmaxf(fmaxf(a4, a5), fmaxf(a6, a7))));
    }
    #pragma unroll
    for (int off = 32; off > 0; off >>= 1) {
        mn = fminf(mn, __shfl_down(mn, off));
        mx = fmaxf(mx, __shfl_down(mx, off));
    }
    __shared__ float smn[4], smx[4];
    int lane = t & 63, wv = t >> 6;
    if (lane == 0) { smn[wv] = mn; smx[wv] = mx; }
    __syncthreads();
    if (t == 0) {
        float bmn = fminf(fminf(smn[0], smn[1]), fminf(smn[2], smn[3]));
        float bmx = fmaxf(fmaxf(smx[0], smx[1]), fmaxf(smx[2], smx[3]));
        atomicMin(&qpa[0], f2ord(bmn));   // device-scope by default
        atomicMax(&qpa[1], f2ord(bmx));
    }
}

// ---------------- Pass 3: quantize, store (q - zp) as exact bf16 ------------
__global__ __launch_bounds__(256) void k_quant(const float* __restrict__ x,
                                               const float* __restrict__ inv_s,
                                               const unsigned int* __restrict__ qpa,
                                               unsigned short* __restrict__ xq) {
    const float mn = ord2f(qpa[0]), mx = ord2f(qpa[1]);
    const float qs = (mx - mn) / QMAXF;       // exact div, matches reference
    const float zp = rintf(-mn / qs);
    const float inv_qs = 1.0f / qs;
    const int t = threadIdx.x;
    const size_t base = (size_t)blockIdx.x * (ROWS_PER_BLK * IN_DIM);
    int c0 = t * 8; if (c0 >= IN_DIM) c0 -= IN_DIM;
    #pragma unroll 3
    for (int j = 0; j < CHUNKS_PER_THREAD; j++) {
        size_t off = base + (size_t)(j * 256 + t) * 8;
        float4 x0 = *(const float4*)(x + off);
        float4 x1 = *(const float4*)(x + off + 4);
        int cj = c0 + CJ_TBL[j]; if (cj >= IN_DIM) cj -= IN_DIM;
        float4 s0 = *(const float4*)(inv_s + cj);
        float4 s1 = *(const float4*)(inv_s + cj + 4);
        float a[8] = { x0.x * s0.x, x0.y * s0.y, x0.z * s0.z, x0.w * s0.w,
                       x1.x * s1.x, x1.y * s1.y, x1.z * s1.z, x1.w * s1.w };
        u16x8 o;
        #pragma unroll
        for (int jj = 0; jj < 8; jj++) {
            float q = rintf(a[jj] * inv_qs) + zp;
            q = fminf(fmaxf(q, 0.0f), QMAXF);
            o[jj] = f2bf(q - zp);             // integer in [-255,255]: exact in bf16
        }
        *(u16x8*)(xq + off) = o;              // 16B store
    }
}

// ---------------- Pass 4: GEMM  C = qs * (A @ Wc^T) + bias ------------------
// A: [M][K] bf16 (q - zp), Wc: [N][K] bf16, C: [M][N] fp32  (R1-exact, BK=32)
#define BM 128
#define BN 128
#define BK 32

__global__ __launch_bounds__(256) void k_gemm(const unsigned short* __restrict__ A,
                                              const unsigned short* __restrict__ Bw,
                                              const float* __restrict__ bias,
                                              const unsigned int* __restrict__ qpa,
                                              float* __restrict__ C) {
    __shared__ __align__(16) unsigned short As[BM * BK];   // 8 KB
    __shared__ __align__(16) unsigned short Bs[BN * BK];   // 8 KB
    const int tid = threadIdx.x;
    const int bm = blockIdx.x, bn = blockIdx.y;
    const int K = IN_DIM, N = OUT_DIM;

    const int r0 = tid >> 2;
    const int c0 = (tid & 3) * 8;
    const unsigned short* ga0 = A  + (size_t)(bm * BM + r0) * K + c0;
    const unsigned short* ga1 = ga0 + (size_t)64 * K;
    const unsigned short* gb0 = Bw + (size_t)(bn * BN + r0) * K + c0;
    const unsigned short* gb1 = gb0 + (size_t)64 * K;
    unsigned short* lA0 = As + tid * 8;
    unsigned short* lA1 = As + tid * 8 + 2048;
    unsigned short* lB0 = Bs + tid * 8;
    unsigned short* lB1 = Bs + tid * 8 + 2048;

    f32x4 acc[4][4];
    #pragma unroll
    for (int mi = 0; mi < 4; mi++)
        #pragma unroll
        for (int ni = 0; ni < 4; ni++)
            acc[mi][ni] = (f32x4)0.0f;

    const int lane = tid & 63, wv = tid >> 6;
    const int wm = (wv & 1) * 64;
    const int wn = (wv >> 1) * 64;
    const int l16 = lane & 15, l4 = lane >> 4;
    const bf16x8* Asv = (const bf16x8*)As;
    const bf16x8* Bsv = (const bf16x8*)Bs;
    const int afo = (wm + l16) * 4 + l4;
    const int bfo = (wn + l16) * 4 + l4;

    for (int k0 = 0; k0 < K; k0 += BK) {
        __builtin_amdgcn_global_load_lds(
            (const __attribute__((address_space(1))) unsigned int*)(ga0 + k0),
            (__attribute__((address_space(3))) unsigned int*)lA0, 16, 0, 0);
        __builtin_amdgcn_global_load_lds(
            (const __attribute__((address_space(1))) unsigned int*)(ga1 + k0),
            (__attribute__((address_space(3))) unsigned int*)lA1, 16, 0, 0);
        __builtin_amdgcn_global_load_lds(
            (const __attribute__((address_space(1))) unsigned int*)(gb0 + k0),
            (__attribute__((address_space(3))) unsigned int*)lB0, 16, 0, 0);
        __builtin_amdgcn_global_load_lds(
            (const __attribute__((address_space(1))) unsigned int*)(gb1 + k0),
            (__attribute__((address_space(3))) unsigned int*)lB1, 16, 0, 0);
        __syncthreads();

        bf16x8 af[4], bf[4];
        #pragma unroll
        for (int mi = 0; mi < 4; mi++) af[mi] = Asv[afo + mi * 64];
        #pragma unroll
        for (int ni = 0; ni < 4; ni++) bf[ni] = Bsv[bfo + ni * 64];
        #pragma unroll
        for (int mi = 0; mi < 4; mi++)
            #pragma unroll
            for (int ni = 0; ni < 4; ni++)
                acc[mi][ni] = __builtin_amdgcn_mfma_f32_16x16x32_bf16(
                    af[mi], bf[ni], acc[mi][ni], 0, 0, 0);
        __syncthreads();
    }

    const float qs = (ord2f(qpa[1]) - ord2f(qpa[0])) / QMAXF;
    #pragma unroll
    for (int mi = 0; mi < 4; mi++) {
        int row0 = bm * BM + wm + mi * 16 + l4 * 4;
        #pragma unroll
        for (int ni = 0; ni < 4; ni++) {
            int col = bn * BN + wn + ni * 16 + l16;
            float bv = bias[col];
            #pragma unroll
            for (int r = 0; r < 4; r++)
                C[(size_t)(row0 + r) * N + col] = acc[mi][ni][r] * qs + bv;
        }
    }
}

extern "C" void kernel_launch(void* const* d_in, const int* in_sizes, int n_in,
                              void* d_out, int out_size, void* d_ws, size_t ws_size,
                              hipStream_t stream) {
    const float* x      = (const float*)d_in[0];
    const float* qw     = (const float*)d_in[1];
    const float* rw     = (const float*)d_in[2];
    const float* lw     = (const float*)d_in[3];
    const float* bias   = (const float*)d_in[4];
    const float* scales = (const float*)d_in[5];

    char* ws = (char*)d_ws;
    // ws layout (16B aligned): xq 75,497,472 | wc 2,654,208 | qpa 16 | inv_s 4,608
    unsigned short* xq = (unsigned short*)ws;
    unsigned short* wc = (unsigned short*)(ws + 75497472);
    unsigned int*  qpa = (unsigned int*)(ws + 75497472 + 2654208);
    float* inv_s       = (float*)(ws + 75497472 + 2654208 + 16);

    k_prep  <<<(OUT_DIM * IN_DIM) / 256, 256, 0, stream>>>(qw, rw, lw, scales, wc, inv_s, qpa);
    k_minmax<<<SBLOCKS, 256, 0, stream>>>(x, inv_s, qpa);
    k_quant <<<SBLOCKS, 256, 0, stream>>>(x, inv_s, qpa, xq);

    dim3 grid(M_DIM / BM, OUT_DIM / BN);   // 256 x 9
    k_gemm<<<grid, 256, 0, stream>>>(xq, wc, bias, qpa, (float*)d_out);
}